// Round 4
// baseline (780.186 us; speedup 1.0000x reference)
//
#include <hip/hip_runtime.h>

#define E_ 8
#define H_ 1024
#define I_ 512
#define NE 9            // 8 routed + 1 shared
#define NTOK 8192

typedef __bf16 bf16;
typedef __bf16 bf16x8 __attribute__((ext_vector_type(8)));
typedef __bf16 bf16x4 __attribute__((ext_vector_type(4)));
typedef float f32x4 __attribute__((ext_vector_type(4)));

__device__ __forceinline__ void gload16(const bf16* g, bf16* l) {
  __builtin_amdgcn_global_load_lds(
      (const __attribute__((address_space(1))) void*)g,
      (__attribute__((address_space(3))) void*)l,
      16, 0, 0);
}

// ---------------- x (fp32) -> Xb (bf16) ----------------
__global__ __launch_bounds__(256) void convert_kernel(
    const float* __restrict__ x, bf16* __restrict__ xb) {
  int i = blockIdx.x * 256 + threadIdx.x;
  f32x4 v = ((const f32x4*)x)[i];
  bf16x4 o = {(bf16)v.x, (bf16)v.y, (bf16)v.z, (bf16)v.w};
  ((bf16x4*)xb)[i] = o;
}

// ---------------- router: per-expert compacted token lists ----------------
__global__ __launch_bounds__(256) void router_kernel(
    const float* __restrict__ x, const float* __restrict__ gw,
    const float* __restrict__ bias, int* __restrict__ cnt,
    int* __restrict__ idx, float* __restrict__ cwp) {
  int t = threadIdx.x;
  int l = t & 63, w = t >> 6;
  int n = blockIdx.x * 4 + w;
  const f32x4* xr = (const f32x4*)(x + (size_t)n * H_ + l * 16);
  float xv[16];
#pragma unroll
  for (int q = 0; q < 4; q++) {
    f32x4 v = xr[q];
    xv[q * 4 + 0] = v.x; xv[q * 4 + 1] = v.y; xv[q * 4 + 2] = v.z; xv[q * 4 + 3] = v.w;
  }
  float s[E_], sc[E_];
#pragma unroll
  for (int e = 0; e < E_; e++) {
    const f32x4* gr = (const f32x4*)(gw + e * H_ + l * 16);
    float acc = 0.f;
#pragma unroll
    for (int q = 0; q < 4; q++) {
      f32x4 g = gr[q];
      acc += xv[q * 4 + 0] * g.x + xv[q * 4 + 1] * g.y + xv[q * 4 + 2] * g.z + xv[q * 4 + 3] * g.w;
    }
#pragma unroll
    for (int off = 32; off > 0; off >>= 1) acc += __shfl_xor(acc, off, 64);
    float sig = 1.f / (1.f + __expf(-acc));
    s[e] = sig;
    sc[e] = sig + bias[e];
  }
  if (l == 0) {
    float gs[4];
#pragma unroll
    for (int g = 0; g < 4; g++) gs[g] = sc[2 * g] + sc[2 * g + 1];
    int g0 = 0;
    for (int g = 1; g < 4; g++) if (gs[g] > gs[g0]) g0 = g;
    int g1 = -1;
    for (int g = 0; g < 4; g++) {
      if (g == g0) continue;
      if (g1 < 0 || gs[g] > gs[g1]) g1 = g;
    }
    int es[4] = {2 * g0, 2 * g0 + 1, 2 * g1, 2 * g1 + 1};
    float wsum = 1e-20f;
    for (int j = 0; j < 4; j++) wsum += s[es[j]];
    float inv = 2.5f / wsum;
    for (int j = 0; j < 4; j++) {
      int e = es[j];
      int p = atomicAdd(&cnt[e], 1);
      idx[e * NTOK + p] = n;
      cwp[e * NTOK + p] = s[e] * inv;
    }
  }
}

// ---------------- weight transpose + fp32->bf16 convert ----------------
// jobs 0..8  : Wg family [1024,512] -> BgT[e] [512,1024]
// jobs 9..17 : Wu family same -> BuT
// jobs 18..26: Wd family [512,1024] -> WdT[e] [1024,512]
__global__ __launch_bounds__(256) void transpose_kernel(
    const float* __restrict__ Wg, const float* __restrict__ Wu,
    const float* __restrict__ Wd, const float* __restrict__ Wgs,
    const float* __restrict__ Wus, const float* __restrict__ Wds,
    bf16* __restrict__ BgT, bf16* __restrict__ BuT, bf16* __restrict__ WdT) {
  __shared__ bf16 tile[32][33];
  int job = blockIdx.x >> 9;
  int tl = blockIdx.x & 511;
  const float* src;
  bf16* dst;
  int C, dst_ld;
  if (job < 18) {
    int e = job % 9;
    if (job < 9) src = (e < 8) ? Wg + (size_t)e * H_ * I_ : Wgs;
    else         src = (e < 8) ? Wu + (size_t)e * H_ * I_ : Wus;
    dst = ((job < 9) ? BgT : BuT) + (size_t)e * I_ * H_;
    C = I_; dst_ld = H_;
  } else {
    int e = job - 18;
    src = (e < 8) ? Wd + (size_t)e * I_ * H_ : Wds;   // [512,1024]
    dst = WdT + (size_t)e * H_ * I_;                  // [1024,512]
    C = H_; dst_ld = I_;
  }
  int n_tc = C >> 5;
  int tr = tl / n_tc, tc = tl % n_tc;
  int tx = threadIdx.x & 31, ty = threadIdx.x >> 5;
#pragma unroll
  for (int j = 0; j < 4; j++) {
    int r = tr * 32 + ty + j * 8;
    tile[ty + j * 8][tx] = (bf16)src[(size_t)r * C + tc * 32 + tx];
  }
  __syncthreads();
#pragma unroll
  for (int j = 0; j < 4; j++) {
    int c = tc * 32 + ty + j * 8;
    dst[(size_t)c * dst_ld + tr * 32 + tx] = tile[tx][ty + j * 8];
  }
}

// LDS tiles [128][64] bf16, XOR-swizzled in 16B chunks (see R2 notes):
// store chunk (l&7) holds global chunk (l&7)^((l>>3)&7); fragment read of
// global chunk q at row r uses chunk q^(r&7); row offsets are multiples of 8
// so swizzle = q^(l&7) -> 2-way conflicts only (free).

// ---------------- GEMM1 (grouped): Tc[e][p,0..511] = cw*silu(X Wg_e)*(X Wu_e) ----------------
// grid.x = 4 (n-tiles of 128 over I=512), grid.y = 9*64 slots (expert, mtile)
__global__ __launch_bounds__(256, 2) void gemm1_kernel(
    const bf16* __restrict__ X, const bf16* __restrict__ BgT,
    const bf16* __restrict__ BuT, const int* __restrict__ idx,
    const float* __restrict__ cwp, const int* __restrict__ cnt,
    bf16* __restrict__ Tc) {
  int slot = blockIdx.y;
  int e = slot >> 6;
  int m0 = (slot & 63) * 128;
  int ne = (e < 8) ? cnt[e] : NTOK;
  if (m0 >= ne) return;

  __shared__ bf16 As[128 * 64], Bgs[128 * 64], Bus[128 * 64];
  int t = threadIdx.x;
  int l = t & 63, w = t >> 6;
  int wm = w >> 1, wn = w & 1;
  int n0 = blockIdx.x * 128;

  f32x4 accg[4][4], accu[4][4];
#pragma unroll
  for (int mi = 0; mi < 4; mi++)
#pragma unroll
    for (int ni = 0; ni < 4; ni++) {
      accg[mi][ni] = (f32x4){0.f, 0.f, 0.f, 0.f};
      accu[mi][ni] = (f32x4){0.f, 0.f, 0.f, 0.f};
    }

  int srow = t >> 3;
  int scol = (((t & 7) ^ ((t >> 3) & 7)) * 8);
  int rid[4];
#pragma unroll
  for (int i = 0; i < 4; i++) {
    int r = m0 + srow + 32 * i;
    rid[i] = (e < 8) ? ((r < ne) ? idx[e * NTOK + r] : 0) : r;
  }
  const bf16* gg = BgT + (size_t)e * I_ * H_ + (size_t)(n0 + srow) * H_ + scol;
  const bf16* gu = BuT + (size_t)e * I_ * H_ + (size_t)(n0 + srow) * H_ + scol;
  bf16* la = As + w * 512;
  bf16* lg = Bgs + w * 512;
  bf16* lu = Bus + w * 512;

  for (int k0 = 0; k0 < H_; k0 += 64) {
#pragma unroll
    for (int i = 0; i < 4; i++) {
      gload16(X + (size_t)rid[i] * H_ + scol + k0, la + i * 2048);
      gload16(gg + (size_t)i * 32 * H_ + k0, lg + i * 2048);
      gload16(gu + (size_t)i * 32 * H_ + k0, lu + i * 2048);
    }
    __syncthreads();
#pragma unroll
    for (int ks = 0; ks < 2; ks++) {
      int ko = (((ks * 4 + (l >> 4)) ^ (l & 7)) * 8);
      int ar = wm * 64 + (l & 15);
      int br = wn * 64 + (l & 15);
      bf16x8 af[4], bg[4], bu[4];
#pragma unroll
      for (int mi = 0; mi < 4; mi++)
        af[mi] = *(const bf16x8*)(As + (ar + mi * 16) * 64 + ko);
#pragma unroll
      for (int ni = 0; ni < 4; ni++) {
        bg[ni] = *(const bf16x8*)(Bgs + (br + ni * 16) * 64 + ko);
        bu[ni] = *(const bf16x8*)(Bus + (br + ni * 16) * 64 + ko);
      }
#pragma unroll
      for (int mi = 0; mi < 4; mi++)
#pragma unroll
        for (int ni = 0; ni < 4; ni++) {
          accg[mi][ni] = __builtin_amdgcn_mfma_f32_16x16x32_bf16(af[mi], bg[ni], accg[mi][ni], 0, 0, 0);
          accu[mi][ni] = __builtin_amdgcn_mfma_f32_16x16x32_bf16(af[mi], bu[ni], accu[mi][ni], 0, 0, 0);
        }
    }
    __syncthreads();
  }
#pragma unroll
  for (int mi = 0; mi < 4; mi++) {
#pragma unroll
    for (int r = 0; r < 4; r++) {
      int lr = wm * 64 + mi * 16 + (l >> 4) * 4 + r;
      int pr = m0 + lr;
      if (pr < ne) {
        float c = (e < 8) ? cwp[e * NTOK + pr] : 1.0f;
#pragma unroll
        for (int ni = 0; ni < 4; ni++) {
          float g = accg[mi][ni][r];
          float u = accu[mi][ni][r];
          float val = c * (g / (1.f + __expf(-g))) * u;
          int col = n0 + wn * 64 + ni * 16 + (l & 15);
          Tc[((size_t)e * NTOK + pr) * I_ + col] = (bf16)val;
        }
      }
    }
  }
}

// ---------------- GEMM2 shared: out = Tc[8] @ WdT[8]^T (plain fp32 store) ----------------
__global__ __launch_bounds__(256, 3) void gemm2s_kernel(
    const bf16* __restrict__ Tc, const bf16* __restrict__ WdT,
    float* __restrict__ out) {
  __shared__ bf16 As[128 * 64], Bs[128 * 64];
  int t = threadIdx.x;
  int l = t & 63, w = t >> 6;
  int wm = w >> 1, wn = w & 1;
  int m0 = blockIdx.y * 128;
  int n0 = blockIdx.x * 128;

  f32x4 acc[4][4];
#pragma unroll
  for (int mi = 0; mi < 4; mi++)
#pragma unroll
    for (int ni = 0; ni < 4; ni++) acc[mi][ni] = (f32x4){0.f, 0.f, 0.f, 0.f};

  int srow = t >> 3;
  int scol = (((t & 7) ^ ((t >> 3) & 7)) * 8);
  const bf16* ga = Tc + (size_t)8 * NTOK * I_ + (size_t)(m0 + srow) * I_ + scol;
  const bf16* gb = WdT + (size_t)8 * H_ * I_ + (size_t)(n0 + srow) * I_ + scol;
  bf16* la = As + w * 512;
  bf16* lb = Bs + w * 512;

  for (int k0 = 0; k0 < I_; k0 += 64) {
#pragma unroll
    for (int i = 0; i < 4; i++) {
      gload16(ga + (size_t)i * 32 * I_ + k0, la + i * 2048);
      gload16(gb + (size_t)i * 32 * I_ + k0, lb + i * 2048);
    }
    __syncthreads();
#pragma unroll
    for (int ks = 0; ks < 2; ks++) {
      int ko = (((ks * 4 + (l >> 4)) ^ (l & 7)) * 8);
      int ar = wm * 64 + (l & 15);
      int br = wn * 64 + (l & 15);
      bf16x8 af[4], bfv[4];
#pragma unroll
      for (int mi = 0; mi < 4; mi++)
        af[mi] = *(const bf16x8*)(As + (ar + mi * 16) * 64 + ko);
#pragma unroll
      for (int ni = 0; ni < 4; ni++)
        bfv[ni] = *(const bf16x8*)(Bs + (br + ni * 16) * 64 + ko);
#pragma unroll
      for (int mi = 0; mi < 4; mi++)
#pragma unroll
        for (int ni = 0; ni < 4; ni++)
          acc[mi][ni] = __builtin_amdgcn_mfma_f32_16x16x32_bf16(af[mi], bfv[ni], acc[mi][ni], 0, 0, 0);
    }
    __syncthreads();
  }
#pragma unroll
  for (int mi = 0; mi < 4; mi++) {
#pragma unroll
    for (int r = 0; r < 4; r++) {
      int row = m0 + wm * 64 + mi * 16 + (l >> 4) * 4 + r;
#pragma unroll
      for (int ni = 0; ni < 4; ni++) {
        int col = n0 + wn * 64 + ni * 16 + (l & 15);
        out[(size_t)row * H_ + col] = acc[mi][ni][r];
      }
    }
  }
}

// ---------------- GEMM2 routed (grouped): out[tok] += Tc[e] @ WdT[e]^T ----------------
// grid.x = 8 (n-tiles over H=1024), grid.y = 8*64 slots
__global__ __launch_bounds__(256, 3) void gemm2r_kernel(
    const bf16* __restrict__ Tc, const bf16* __restrict__ WdT,
    const int* __restrict__ idx, const int* __restrict__ cnt,
    float* __restrict__ out) {
  int slot = blockIdx.y;
  int e = slot >> 6;
  int m0 = (slot & 63) * 128;
  int ne = cnt[e];
  if (m0 >= ne) return;

  __shared__ bf16 As[128 * 64], Bs[128 * 64];
  int t = threadIdx.x;
  int l = t & 63, w = t >> 6;
  int wm = w >> 1, wn = w & 1;
  int n0 = blockIdx.x * 128;

  f32x4 acc[4][4];
#pragma unroll
  for (int mi = 0; mi < 4; mi++)
#pragma unroll
    for (int ni = 0; ni < 4; ni++) acc[mi][ni] = (f32x4){0.f, 0.f, 0.f, 0.f};

  int srow = t >> 3;
  int scol = (((t & 7) ^ ((t >> 3) & 7)) * 8);
  const bf16* ga = Tc + (size_t)e * NTOK * I_ + (size_t)(m0 + srow) * I_ + scol;
  const bf16* gb = WdT + (size_t)e * H_ * I_ + (size_t)(n0 + srow) * I_ + scol;
  bf16* la = As + w * 512;
  bf16* lb = Bs + w * 512;

  for (int k0 = 0; k0 < I_; k0 += 64) {
#pragma unroll
    for (int i = 0; i < 4; i++) {
      gload16(ga + (size_t)i * 32 * I_ + k0, la + i * 2048);
      gload16(gb + (size_t)i * 32 * I_ + k0, lb + i * 2048);
    }
    __syncthreads();
#pragma unroll
    for (int ks = 0; ks < 2; ks++) {
      int ko = (((ks * 4 + (l >> 4)) ^ (l & 7)) * 8);
      int ar = wm * 64 + (l & 15);
      int br = wn * 64 + (l & 15);
      bf16x8 af[4], bfv[4];
#pragma unroll
      for (int mi = 0; mi < 4; mi++)
        af[mi] = *(const bf16x8*)(As + (ar + mi * 16) * 64 + ko);
#pragma unroll
      for (int ni = 0; ni < 4; ni++)
        bfv[ni] = *(const bf16x8*)(Bs + (br + ni * 16) * 64 + ko);
#pragma unroll
      for (int mi = 0; mi < 4; mi++)
#pragma unroll
        for (int ni = 0; ni < 4; ni++)
          acc[mi][ni] = __builtin_amdgcn_mfma_f32_16x16x32_bf16(af[mi], bfv[ni], acc[mi][ni], 0, 0, 0);
    }
    __syncthreads();
  }
#pragma unroll
  for (int mi = 0; mi < 4; mi++) {
#pragma unroll
    for (int r = 0; r < 4; r++) {
      int lr = wm * 64 + mi * 16 + (l >> 4) * 4 + r;
      int pr = m0 + lr;
      if (pr < ne) {
        int tok = idx[e * NTOK + pr];
#pragma unroll
        for (int ni = 0; ni < 4; ni++) {
          int col = n0 + wn * 64 + ni * 16 + (l & 15);
          atomicAdd(&out[(size_t)tok * H_ + col], acc[mi][ni][r]);
        }
      }
    }
  }
}

extern "C" void kernel_launch(void* const* d_in, const int* in_sizes, int n_in,
                              void* d_out, int out_size, void* d_ws, size_t ws_size,
                              hipStream_t stream) {
  const float* x   = (const float*)d_in[0];
  const float* gw  = (const float*)d_in[1];
  const float* cb  = (const float*)d_in[2];
  const float* Wg  = (const float*)d_in[3];
  const float* Wu  = (const float*)d_in[4];
  const float* Wd  = (const float*)d_in[5];
  const float* Wgs = (const float*)d_in[6];
  const float* Wus = (const float*)d_in[7];
  const float* Wds = (const float*)d_in[8];

  char* ws = (char*)d_ws;
  size_t off = 0;
  int*   cnt = (int*)(ws + off);  off += 64;
  int*   idx = (int*)(ws + off);  off += (size_t)E_ * NTOK * 4;
  float* cwp = (float*)(ws + off); off += (size_t)E_ * NTOK * 4;
  bf16* BgT = (bf16*)(ws + off);  off += (size_t)NE * I_ * H_ * 2;
  bf16* BuT = (bf16*)(ws + off);  off += (size_t)NE * I_ * H_ * 2;
  bf16* WdT = (bf16*)(ws + off);  off += (size_t)NE * H_ * I_ * 2;
  bf16* Xb  = (bf16*)(ws + off);  off += (size_t)NTOK * H_ * 2;
  bf16* Tc  = (bf16*)(ws + off);  off += (size_t)NE * NTOK * I_ * 2;

  hipMemsetAsync(cnt, 0, 64, stream);
  hipLaunchKernelGGL(convert_kernel, dim3(NTOK * H_ / 1024), dim3(256), 0, stream,
                     x, Xb);
  hipLaunchKernelGGL(transpose_kernel, dim3(27 * 512), dim3(256), 0, stream,
                     Wg, Wu, Wd, Wgs, Wus, Wds, BgT, BuT, WdT);
  hipLaunchKernelGGL(router_kernel, dim3(NTOK / 4), dim3(256), 0, stream,
                     x, gw, cb, cnt, idx, cwp);
  hipLaunchKernelGGL(gemm1_kernel, dim3(4, NE * 64), dim3(256), 0, stream,
                     Xb, BgT, BuT, idx, cwp, cnt, Tc);
  hipLaunchKernelGGL(gemm2s_kernel, dim3(8, 64), dim3(256), 0, stream,
                     Tc, WdT, (float*)d_out);
  hipLaunchKernelGGL(gemm2r_kernel, dim3(8, E_ * 64), dim3(256), 0, stream,
                     Tc, WdT, idx, cnt, (float*)d_out);
}

// Round 5
// 422.386 us; speedup vs baseline: 1.8471x; 1.8471x over previous
//
#include <hip/hip_runtime.h>

#define E_ 8
#define H_ 1024
#define I_ 512
#define NE 9            // 8 routed + 1 shared
#define NTOK 8192

typedef __bf16 bf16;
typedef __bf16 bf16x8 __attribute__((ext_vector_type(8)));
typedef __bf16 bf16x4 __attribute__((ext_vector_type(4)));
typedef float f32x4 __attribute__((ext_vector_type(4)));

__device__ __forceinline__ void gload16(const bf16* g, bf16* l) {
  __builtin_amdgcn_global_load_lds(
      (const __attribute__((address_space(1))) void*)g,
      (__attribute__((address_space(3))) void*)l,
      16, 0, 0);
}

// ---------------- x (fp32) -> Xb (bf16) ----------------
__global__ __launch_bounds__(256) void convert_kernel(
    const float* __restrict__ x, bf16* __restrict__ xb) {
  int i = blockIdx.x * 256 + threadIdx.x;
  f32x4 v = ((const f32x4*)x)[i];
  bf16x4 o = {(bf16)v.x, (bf16)v.y, (bf16)v.z, (bf16)v.w};
  ((bf16x4*)xb)[i] = o;
}

// ---------------- router: per-token top-4 (no atomics) ----------------
__global__ __launch_bounds__(256) void router_kernel(
    const float* __restrict__ x, const float* __restrict__ gw,
    const float* __restrict__ bias, int4* __restrict__ topk_e,
    float4* __restrict__ topk_w) {
  int t = threadIdx.x;
  int l = t & 63, w = t >> 6;
  int n = blockIdx.x * 4 + w;
  const f32x4* xr = (const f32x4*)(x + (size_t)n * H_ + l * 16);
  float xv[16];
#pragma unroll
  for (int q = 0; q < 4; q++) {
    f32x4 v = xr[q];
    xv[q * 4 + 0] = v.x; xv[q * 4 + 1] = v.y; xv[q * 4 + 2] = v.z; xv[q * 4 + 3] = v.w;
  }
  float s[E_], sc[E_];
#pragma unroll
  for (int e = 0; e < E_; e++) {
    const f32x4* gr = (const f32x4*)(gw + e * H_ + l * 16);
    float acc = 0.f;
#pragma unroll
    for (int q = 0; q < 4; q++) {
      f32x4 g = gr[q];
      acc += xv[q * 4 + 0] * g.x + xv[q * 4 + 1] * g.y + xv[q * 4 + 2] * g.z + xv[q * 4 + 3] * g.w;
    }
#pragma unroll
    for (int off = 32; off > 0; off >>= 1) acc += __shfl_xor(acc, off, 64);
    float sig = 1.f / (1.f + __expf(-acc));
    s[e] = sig;
    sc[e] = sig + bias[e];
  }
  if (l == 0) {
    float gs[4];
#pragma unroll
    for (int g = 0; g < 4; g++) gs[g] = sc[2 * g] + sc[2 * g + 1];
    int g0 = 0;
    for (int g = 1; g < 4; g++) if (gs[g] > gs[g0]) g0 = g;
    int g1 = -1;
    for (int g = 0; g < 4; g++) {
      if (g == g0) continue;
      if (g1 < 0 || gs[g] > gs[g1]) g1 = g;
    }
    int es[4] = {2 * g0, 2 * g0 + 1, 2 * g1, 2 * g1 + 1};
    float wsum = 1e-20f;
    for (int j = 0; j < 4; j++) wsum += s[es[j]];
    float inv = 2.5f / wsum;
    topk_e[n] = (int4){es[0], es[1], es[2], es[3]};
    topk_w[n] = (float4){s[es[0]] * inv, s[es[1]] * inv, s[es[2]] * inv, s[es[3]] * inv};
  }
}

// ---------------- compaction: per-expert token lists, block-aggregated atomics ----------------
__global__ __launch_bounds__(256) void compact_kernel(
    const int4* __restrict__ topk_e, const float4* __restrict__ topk_w,
    int* __restrict__ cnt, int* __restrict__ idx, float* __restrict__ cwp) {
  __shared__ int hist[E_];
  __shared__ int base[E_];
  int t = threadIdx.x;
  if (t < E_) hist[t] = 0;
  __syncthreads();
  int n = blockIdx.x * 256 + t;
  int4 e4 = topk_e[n];
  float4 w4 = topk_w[n];
  int le[4] = {e4.x, e4.y, e4.z, e4.w};
  float lw[4] = {w4.x, w4.y, w4.z, w4.w};
  int lpos[4];
#pragma unroll
  for (int j = 0; j < 4; j++) lpos[j] = atomicAdd(&hist[le[j]], 1);
  __syncthreads();
  if (t < E_) base[t] = atomicAdd(&cnt[t], hist[t]);   // 8 global atomics / block
  __syncthreads();
#pragma unroll
  for (int j = 0; j < 4; j++) {
    int p = base[le[j]] + lpos[j];
    idx[le[j] * NTOK + p] = n;
    cwp[le[j] * NTOK + p] = lw[j];
  }
}

// ---------------- weight transpose + fp32->bf16 convert ----------------
// jobs 0..8  : Wg family [1024,512] -> BgT[e] [512,1024]
// jobs 9..17 : Wu family same -> BuT
// jobs 18..26: Wd family [512,1024] -> WdT[e] [1024,512]
__global__ __launch_bounds__(256) void transpose_kernel(
    const float* __restrict__ Wg, const float* __restrict__ Wu,
    const float* __restrict__ Wd, const float* __restrict__ Wgs,
    const float* __restrict__ Wus, const float* __restrict__ Wds,
    bf16* __restrict__ BgT, bf16* __restrict__ BuT, bf16* __restrict__ WdT) {
  __shared__ bf16 tile[32][33];
  int job = blockIdx.x >> 9;
  int tl = blockIdx.x & 511;
  const float* src;
  bf16* dst;
  int C, dst_ld;
  if (job < 18) {
    int e = job % 9;
    if (job < 9) src = (e < 8) ? Wg + (size_t)e * H_ * I_ : Wgs;
    else         src = (e < 8) ? Wu + (size_t)e * H_ * I_ : Wus;
    dst = ((job < 9) ? BgT : BuT) + (size_t)e * I_ * H_;
    C = I_; dst_ld = H_;
  } else {
    int e = job - 18;
    src = (e < 8) ? Wd + (size_t)e * I_ * H_ : Wds;   // [512,1024]
    dst = WdT + (size_t)e * H_ * I_;                  // [1024,512]
    C = H_; dst_ld = I_;
  }
  int n_tc = C >> 5;
  int tr = tl / n_tc, tc = tl % n_tc;
  int tx = threadIdx.x & 31, ty = threadIdx.x >> 5;
#pragma unroll
  for (int j = 0; j < 4; j++) {
    int r = tr * 32 + ty + j * 8;
    tile[ty + j * 8][tx] = (bf16)src[(size_t)r * C + tc * 32 + tx];
  }
  __syncthreads();
#pragma unroll
  for (int j = 0; j < 4; j++) {
    int c = tc * 32 + ty + j * 8;
    dst[(size_t)c * dst_ld + tr * 32 + tx] = tile[tx][ty + j * 8];
  }
}

// LDS tiles [128][64] bf16, XOR-swizzled in 16B chunks (see R2 notes):
// store chunk (l&7) holds global chunk (l&7)^((l>>3)&7); fragment read of
// global chunk q at row r uses chunk q^(r&7); row offsets are multiples of 8
// so swizzle = q^(l&7) -> 2-way conflicts only (free).

// ---------------- GEMM1 (grouped): Tc[e][p,0..511] = cw*silu(X Wg_e)*(X Wu_e) ----------------
__global__ __launch_bounds__(256, 2) void gemm1_kernel(
    const bf16* __restrict__ X, const bf16* __restrict__ BgT,
    const bf16* __restrict__ BuT, const int* __restrict__ idx,
    const float* __restrict__ cwp, const int* __restrict__ cnt,
    bf16* __restrict__ Tc) {
  int slot = blockIdx.y;
  int e = slot >> 6;
  int m0 = (slot & 63) * 128;
  int ne = (e < 8) ? cnt[e] : NTOK;
  if (m0 >= ne) return;

  __shared__ bf16 As[128 * 64], Bgs[128 * 64], Bus[128 * 64];
  int t = threadIdx.x;
  int l = t & 63, w = t >> 6;
  int wm = w >> 1, wn = w & 1;
  int n0 = blockIdx.x * 128;

  f32x4 accg[4][4], accu[4][4];
#pragma unroll
  for (int mi = 0; mi < 4; mi++)
#pragma unroll
    for (int ni = 0; ni < 4; ni++) {
      accg[mi][ni] = (f32x4){0.f, 0.f, 0.f, 0.f};
      accu[mi][ni] = (f32x4){0.f, 0.f, 0.f, 0.f};
    }

  int srow = t >> 3;
  int scol = (((t & 7) ^ ((t >> 3) & 7)) * 8);
  int rid[4];
#pragma unroll
  for (int i = 0; i < 4; i++) {
    int r = m0 + srow + 32 * i;
    rid[i] = (e < 8) ? ((r < ne) ? idx[e * NTOK + r] : 0) : r;
  }
  const bf16* gg = BgT + (size_t)e * I_ * H_ + (size_t)(n0 + srow) * H_ + scol;
  const bf16* gu = BuT + (size_t)e * I_ * H_ + (size_t)(n0 + srow) * H_ + scol;
  bf16* la = As + w * 512;
  bf16* lg = Bgs + w * 512;
  bf16* lu = Bus + w * 512;

  for (int k0 = 0; k0 < H_; k0 += 64) {
#pragma unroll
    for (int i = 0; i < 4; i++) {
      gload16(X + (size_t)rid[i] * H_ + scol + k0, la + i * 2048);
      gload16(gg + (size_t)i * 32 * H_ + k0, lg + i * 2048);
      gload16(gu + (size_t)i * 32 * H_ + k0, lu + i * 2048);
    }
    __syncthreads();
#pragma unroll
    for (int ks = 0; ks < 2; ks++) {
      int ko = (((ks * 4 + (l >> 4)) ^ (l & 7)) * 8);
      int ar = wm * 64 + (l & 15);
      int br = wn * 64 + (l & 15);
      bf16x8 af[4], bg[4], bu[4];
#pragma unroll
      for (int mi = 0; mi < 4; mi++)
        af[mi] = *(const bf16x8*)(As + (ar + mi * 16) * 64 + ko);
#pragma unroll
      for (int ni = 0; ni < 4; ni++) {
        bg[ni] = *(const bf16x8*)(Bgs + (br + ni * 16) * 64 + ko);
        bu[ni] = *(const bf16x8*)(Bus + (br + ni * 16) * 64 + ko);
      }
#pragma unroll
      for (int mi = 0; mi < 4; mi++)
#pragma unroll
        for (int ni = 0; ni < 4; ni++) {
          accg[mi][ni] = __builtin_amdgcn_mfma_f32_16x16x32_bf16(af[mi], bg[ni], accg[mi][ni], 0, 0, 0);
          accu[mi][ni] = __builtin_amdgcn_mfma_f32_16x16x32_bf16(af[mi], bu[ni], accu[mi][ni], 0, 0, 0);
        }
    }
    __syncthreads();
  }
#pragma unroll
  for (int mi = 0; mi < 4; mi++) {
#pragma unroll
    for (int r = 0; r < 4; r++) {
      int lr = wm * 64 + mi * 16 + (l >> 4) * 4 + r;
      int pr = m0 + lr;
      if (pr < ne) {
        float c = (e < 8) ? cwp[e * NTOK + pr] : 1.0f;
#pragma unroll
        for (int ni = 0; ni < 4; ni++) {
          float g = accg[mi][ni][r];
          float u = accu[mi][ni][r];
          float val = c * (g / (1.f + __expf(-g))) * u;
          int col = n0 + wn * 64 + ni * 16 + (l & 15);
          Tc[((size_t)e * NTOK + pr) * I_ + col] = (bf16)val;
        }
      }
    }
  }
}

// ---------------- GEMM2 shared: out = Tc[8] @ WdT[8]^T (plain fp32 store) ----------------
__global__ __launch_bounds__(256, 3) void gemm2s_kernel(
    const bf16* __restrict__ Tc, const bf16* __restrict__ WdT,
    float* __restrict__ out) {
  __shared__ bf16 As[128 * 64], Bs[128 * 64];
  int t = threadIdx.x;
  int l = t & 63, w = t >> 6;
  int wm = w >> 1, wn = w & 1;
  int m0 = blockIdx.y * 128;
  int n0 = blockIdx.x * 128;

  f32x4 acc[4][4];
#pragma unroll
  for (int mi = 0; mi < 4; mi++)
#pragma unroll
    for (int ni = 0; ni < 4; ni++) acc[mi][ni] = (f32x4){0.f, 0.f, 0.f, 0.f};

  int srow = t >> 3;
  int scol = (((t & 7) ^ ((t >> 3) & 7)) * 8);
  const bf16* ga = Tc + (size_t)8 * NTOK * I_ + (size_t)(m0 + srow) * I_ + scol;
  const bf16* gb = WdT + (size_t)8 * H_ * I_ + (size_t)(n0 + srow) * I_ + scol;
  bf16* la = As + w * 512;
  bf16* lb = Bs + w * 512;

  for (int k0 = 0; k0 < I_; k0 += 64) {
#pragma unroll
    for (int i = 0; i < 4; i++) {
      gload16(ga + (size_t)i * 32 * I_ + k0, la + i * 2048);
      gload16(gb + (size_t)i * 32 * I_ + k0, lb + i * 2048);
    }
    __syncthreads();
#pragma unroll
    for (int ks = 0; ks < 2; ks++) {
      int ko = (((ks * 4 + (l >> 4)) ^ (l & 7)) * 8);
      int ar = wm * 64 + (l & 15);
      int br = wn * 64 + (l & 15);
      bf16x8 af[4], bfv[4];
#pragma unroll
      for (int mi = 0; mi < 4; mi++)
        af[mi] = *(const bf16x8*)(As + (ar + mi * 16) * 64 + ko);
#pragma unroll
      for (int ni = 0; ni < 4; ni++)
        bfv[ni] = *(const bf16x8*)(Bs + (br + ni * 16) * 64 + ko);
#pragma unroll
      for (int mi = 0; mi < 4; mi++)
#pragma unroll
        for (int ni = 0; ni < 4; ni++)
          acc[mi][ni] = __builtin_amdgcn_mfma_f32_16x16x32_bf16(af[mi], bfv[ni], acc[mi][ni], 0, 0, 0);
    }
    __syncthreads();
  }
#pragma unroll
  for (int mi = 0; mi < 4; mi++) {
#pragma unroll
    for (int r = 0; r < 4; r++) {
      int row = m0 + wm * 64 + mi * 16 + (l >> 4) * 4 + r;
#pragma unroll
      for (int ni = 0; ni < 4; ni++) {
        int col = n0 + wn * 64 + ni * 16 + (l & 15);
        out[(size_t)row * H_ + col] = acc[mi][ni][r];
      }
    }
  }
}

// ---------------- GEMM2 routed (grouped): out[tok] += Tc[e] @ WdT[e]^T ----------------
__global__ __launch_bounds__(256, 3) void gemm2r_kernel(
    const bf16* __restrict__ Tc, const bf16* __restrict__ WdT,
    const int* __restrict__ idx, const int* __restrict__ cnt,
    float* __restrict__ out) {
  int slot = blockIdx.y;
  int e = slot >> 6;
  int m0 = (slot & 63) * 128;
  int ne = cnt[e];
  if (m0 >= ne) return;

  __shared__ bf16 As[128 * 64], Bs[128 * 64];
  int t = threadIdx.x;
  int l = t & 63, w = t >> 6;
  int wm = w >> 1, wn = w & 1;
  int n0 = blockIdx.x * 128;

  f32x4 acc[4][4];
#pragma unroll
  for (int mi = 0; mi < 4; mi++)
#pragma unroll
    for (int ni = 0; ni < 4; ni++) acc[mi][ni] = (f32x4){0.f, 0.f, 0.f, 0.f};

  int srow = t >> 3;
  int scol = (((t & 7) ^ ((t >> 3) & 7)) * 8);
  const bf16* ga = Tc + (size_t)e * NTOK * I_ + (size_t)(m0 + srow) * I_ + scol;
  const bf16* gb = WdT + (size_t)e * H_ * I_ + (size_t)(n0 + srow) * I_ + scol;
  bf16* la = As + w * 512;
  bf16* lb = Bs + w * 512;

  for (int k0 = 0; k0 < I_; k0 += 64) {
#pragma unroll
    for (int i = 0; i < 4; i++) {
      gload16(ga + (size_t)i * 32 * I_ + k0, la + i * 2048);
      gload16(gb + (size_t)i * 32 * I_ + k0, lb + i * 2048);
    }
    __syncthreads();
#pragma unroll
    for (int ks = 0; ks < 2; ks++) {
      int ko = (((ks * 4 + (l >> 4)) ^ (l & 7)) * 8);
      int ar = wm * 64 + (l & 15);
      int br = wn * 64 + (l & 15);
      bf16x8 af[4], bfv[4];
#pragma unroll
      for (int mi = 0; mi < 4; mi++)
        af[mi] = *(const bf16x8*)(As + (ar + mi * 16) * 64 + ko);
#pragma unroll
      for (int ni = 0; ni < 4; ni++)
        bfv[ni] = *(const bf16x8*)(Bs + (br + ni * 16) * 64 + ko);
#pragma unroll
      for (int mi = 0; mi < 4; mi++)
#pragma unroll
        for (int ni = 0; ni < 4; ni++)
          acc[mi][ni] = __builtin_amdgcn_mfma_f32_16x16x32_bf16(af[mi], bfv[ni], acc[mi][ni], 0, 0, 0);
    }
    __syncthreads();
  }
#pragma unroll
  for (int mi = 0; mi < 4; mi++) {
#pragma unroll
    for (int r = 0; r < 4; r++) {
      int lr = wm * 64 + mi * 16 + (l >> 4) * 4 + r;
      int pr = m0 + lr;
      if (pr < ne) {
        int tok = idx[e * NTOK + pr];
#pragma unroll
        for (int ni = 0; ni < 4; ni++) {
          int col = n0 + wn * 64 + ni * 16 + (l & 15);
          atomicAdd(&out[(size_t)tok * H_ + col], acc[mi][ni][r]);
        }
      }
    }
  }
}

extern "C" void kernel_launch(void* const* d_in, const int* in_sizes, int n_in,
                              void* d_out, int out_size, void* d_ws, size_t ws_size,
                              hipStream_t stream) {
  const float* x   = (const float*)d_in[0];
  const float* gw  = (const float*)d_in[1];
  const float* cb  = (const float*)d_in[2];
  const float* Wg  = (const float*)d_in[3];
  const float* Wu  = (const float*)d_in[4];
  const float* Wd  = (const float*)d_in[5];
  const float* Wgs = (const float*)d_in[6];
  const float* Wus = (const float*)d_in[7];
  const float* Wds = (const float*)d_in[8];

  char* ws = (char*)d_ws;
  size_t off = 0;
  int*    cnt    = (int*)(ws + off);    off += 64;
  int*    idx    = (int*)(ws + off);    off += (size_t)E_ * NTOK * 4;
  float*  cwp    = (float*)(ws + off);  off += (size_t)E_ * NTOK * 4;
  int4*   topk_e = (int4*)(ws + off);   off += (size_t)NTOK * 16;
  float4* topk_w = (float4*)(ws + off); off += (size_t)NTOK * 16;
  bf16* BgT = (bf16*)(ws + off);  off += (size_t)NE * I_ * H_ * 2;
  bf16* BuT = (bf16*)(ws + off);  off += (size_t)NE * I_ * H_ * 2;
  bf16* WdT = (bf16*)(ws + off);  off += (size_t)NE * H_ * I_ * 2;
  bf16* Xb  = (bf16*)(ws + off);  off += (size_t)NTOK * H_ * 2;
  bf16* Tc  = (bf16*)(ws + off);  off += (size_t)NE * NTOK * I_ * 2;

  hipMemsetAsync(cnt, 0, 64, stream);
  hipLaunchKernelGGL(convert_kernel, dim3(NTOK * H_ / 1024), dim3(256), 0, stream,
                     x, Xb);
  hipLaunchKernelGGL(transpose_kernel, dim3(27 * 512), dim3(256), 0, stream,
                     Wg, Wu, Wd, Wgs, Wus, Wds, BgT, BuT, WdT);
  hipLaunchKernelGGL(router_kernel, dim3(NTOK / 4), dim3(256), 0, stream,
                     x, gw, cb, topk_e, topk_w);
  hipLaunchKernelGGL(compact_kernel, dim3(NTOK / 256), dim3(256), 0, stream,
                     topk_e, topk_w, cnt, idx, cwp);
  hipLaunchKernelGGL(gemm1_kernel, dim3(4, NE * 64), dim3(256), 0, stream,
                     Xb, BgT, BuT, idx, cwp, cnt, Tc);
  hipLaunchKernelGGL(gemm2s_kernel, dim3(8, 64), dim3(256), 0, stream,
                     Tc, WdT, (float*)d_out);
  hipLaunchKernelGGL(gemm2r_kernel, dim3(8, E_ * 64), dim3(256), 0, stream,
                     Tc, WdT, idx, cnt, (float*)d_out);
}

// Round 6
// 387.938 us; speedup vs baseline: 2.0111x; 1.0888x over previous
//
#include <hip/hip_runtime.h>

#define E_ 8
#define H_ 1024
#define I_ 512
#define NE 9            // 8 routed + 1 shared
#define NTOK 8192

typedef __bf16 bf16;
typedef __bf16 bf16x8 __attribute__((ext_vector_type(8)));
typedef __bf16 bf16x4 __attribute__((ext_vector_type(4)));
typedef float f32x4 __attribute__((ext_vector_type(4)));

__device__ __forceinline__ void gload16(const bf16* g, bf16* l) {
  __builtin_amdgcn_global_load_lds(
      (const __attribute__((address_space(1))) void*)g,
      (__attribute__((address_space(3))) void*)l,
      16, 0, 0);
}

// ---------------- x (fp32) -> Xb (bf16) ----------------
__global__ __launch_bounds__(256) void convert_kernel(
    const float* __restrict__ x, bf16* __restrict__ xb) {
  int i = blockIdx.x * 256 + threadIdx.x;
  f32x4 v = ((const f32x4*)x)[i];
  bf16x4 o = {(bf16)v.x, (bf16)v.y, (bf16)v.z, (bf16)v.w};
  ((bf16x4*)xb)[i] = o;
}

// ---------------- router: per-token top-4 (no atomics) ----------------
__global__ __launch_bounds__(256) void router_kernel(
    const float* __restrict__ x, const float* __restrict__ gw,
    const float* __restrict__ bias, int4* __restrict__ topk_e,
    float4* __restrict__ topk_w) {
  int t = threadIdx.x;
  int l = t & 63, w = t >> 6;
  int n = blockIdx.x * 4 + w;
  const f32x4* xr = (const f32x4*)(x + (size_t)n * H_ + l * 16);
  float xv[16];
#pragma unroll
  for (int q = 0; q < 4; q++) {
    f32x4 v = xr[q];
    xv[q * 4 + 0] = v.x; xv[q * 4 + 1] = v.y; xv[q * 4 + 2] = v.z; xv[q * 4 + 3] = v.w;
  }
  float s[E_], sc[E_];
#pragma unroll
  for (int e = 0; e < E_; e++) {
    const f32x4* gr = (const f32x4*)(gw + e * H_ + l * 16);
    float acc = 0.f;
#pragma unroll
    for (int q = 0; q < 4; q++) {
      f32x4 g = gr[q];
      acc += xv[q * 4 + 0] * g.x + xv[q * 4 + 1] * g.y + xv[q * 4 + 2] * g.z + xv[q * 4 + 3] * g.w;
    }
#pragma unroll
    for (int off = 32; off > 0; off >>= 1) acc += __shfl_xor(acc, off, 64);
    float sig = 1.f / (1.f + __expf(-acc));
    s[e] = sig;
    sc[e] = sig + bias[e];
  }
  if (l == 0) {
    float gs[4];
#pragma unroll
    for (int g = 0; g < 4; g++) gs[g] = sc[2 * g] + sc[2 * g + 1];
    int g0 = 0;
    for (int g = 1; g < 4; g++) if (gs[g] > gs[g0]) g0 = g;
    int g1 = -1;
    for (int g = 0; g < 4; g++) {
      if (g == g0) continue;
      if (g1 < 0 || gs[g] > gs[g1]) g1 = g;
    }
    int es[4] = {2 * g0, 2 * g0 + 1, 2 * g1, 2 * g1 + 1};
    float wsum = 1e-20f;
    for (int j = 0; j < 4; j++) wsum += s[es[j]];
    float inv = 2.5f / wsum;
    topk_e[n] = (int4){es[0], es[1], es[2], es[3]};
    topk_w[n] = (float4){s[es[0]] * inv, s[es[1]] * inv, s[es[2]] * inv, s[es[3]] * inv};
  }
}

// ---------------- compaction: per-expert token lists, block-aggregated atomics ----------------
__global__ __launch_bounds__(256) void compact_kernel(
    const int4* __restrict__ topk_e, const float4* __restrict__ topk_w,
    int* __restrict__ cnt, int* __restrict__ idx, float* __restrict__ cwp,
    int* __restrict__ tokpos) {
  __shared__ int hist[E_];
  __shared__ int base[E_];
  int t = threadIdx.x;
  if (t < E_) hist[t] = 0;
  __syncthreads();
  int n = blockIdx.x * 256 + t;
  int4 e4 = topk_e[n];
  float4 w4 = topk_w[n];
  int le[4] = {e4.x, e4.y, e4.z, e4.w};
  float lw[4] = {w4.x, w4.y, w4.z, w4.w};
  int lpos[4];
#pragma unroll
  for (int j = 0; j < 4; j++) lpos[j] = atomicAdd(&hist[le[j]], 1);
  __syncthreads();
  if (t < E_) base[t] = atomicAdd(&cnt[t], hist[t]);   // 8 global atomics / block
  __syncthreads();
#pragma unroll
  for (int j = 0; j < 4; j++) {
    int p = base[le[j]] + lpos[j];
    idx[le[j] * NTOK + p] = n;
    cwp[le[j] * NTOK + p] = lw[j];
    tokpos[n * 4 + j] = (le[j] << 13) | p;     // packed (expert, pos)
  }
}

// ---------------- weight transpose + fp32->bf16 convert ----------------
// jobs 0..8  : Wg family [1024,512] -> BgT[e] [512,1024]
// jobs 9..17 : Wu family same -> BuT
// jobs 18..26: Wd family [512,1024] -> WdT[e] [1024,512]
__global__ __launch_bounds__(256) void transpose_kernel(
    const float* __restrict__ Wg, const float* __restrict__ Wu,
    const float* __restrict__ Wd, const float* __restrict__ Wgs,
    const float* __restrict__ Wus, const float* __restrict__ Wds,
    bf16* __restrict__ BgT, bf16* __restrict__ BuT, bf16* __restrict__ WdT) {
  __shared__ bf16 tile[32][33];
  int job = blockIdx.x >> 9;
  int tl = blockIdx.x & 511;
  const float* src;
  bf16* dst;
  int C, dst_ld;
  if (job < 18) {
    int e = job % 9;
    if (job < 9) src = (e < 8) ? Wg + (size_t)e * H_ * I_ : Wgs;
    else         src = (e < 8) ? Wu + (size_t)e * H_ * I_ : Wus;
    dst = ((job < 9) ? BgT : BuT) + (size_t)e * I_ * H_;
    C = I_; dst_ld = H_;
  } else {
    int e = job - 18;
    src = (e < 8) ? Wd + (size_t)e * I_ * H_ : Wds;   // [512,1024]
    dst = WdT + (size_t)e * H_ * I_;                  // [1024,512]
    C = H_; dst_ld = I_;
  }
  int n_tc = C >> 5;
  int tr = tl / n_tc, tc = tl % n_tc;
  int tx = threadIdx.x & 31, ty = threadIdx.x >> 5;
#pragma unroll
  for (int j = 0; j < 4; j++) {
    int r = tr * 32 + ty + j * 8;
    tile[ty + j * 8][tx] = (bf16)src[(size_t)r * C + tc * 32 + tx];
  }
  __syncthreads();
#pragma unroll
  for (int j = 0; j < 4; j++) {
    int c = tc * 32 + ty + j * 8;
    dst[(size_t)c * dst_ld + tr * 32 + tx] = tile[tx][ty + j * 8];
  }
}

// LDS tiles [128][64] bf16, XOR-swizzled in 16B chunks (see R2 notes):
// store chunk (l&7) holds global chunk (l&7)^((l>>3)&7); fragment read of
// global chunk q at row r uses chunk q^(r&7); row offsets are multiples of 8
// so swizzle = q^(l&7) -> 2-way conflicts only (free).

// ---------------- GEMM1 (grouped): Tc[e][p,0..511] = cw*silu(X Wg_e)*(X Wu_e) ----------------
__global__ __launch_bounds__(256, 2) void gemm1_kernel(
    const bf16* __restrict__ X, const bf16* __restrict__ BgT,
    const bf16* __restrict__ BuT, const int* __restrict__ idx,
    const float* __restrict__ cwp, const int* __restrict__ cnt,
    bf16* __restrict__ Tc) {
  int slot = blockIdx.y;
  int e = slot >> 6;
  int m0 = (slot & 63) * 128;
  int ne = (e < 8) ? cnt[e] : NTOK;
  if (m0 >= ne) return;

  __shared__ bf16 As[128 * 64], Bgs[128 * 64], Bus[128 * 64];
  int t = threadIdx.x;
  int l = t & 63, w = t >> 6;
  int wm = w >> 1, wn = w & 1;
  int n0 = blockIdx.x * 128;

  f32x4 accg[4][4], accu[4][4];
#pragma unroll
  for (int mi = 0; mi < 4; mi++)
#pragma unroll
    for (int ni = 0; ni < 4; ni++) {
      accg[mi][ni] = (f32x4){0.f, 0.f, 0.f, 0.f};
      accu[mi][ni] = (f32x4){0.f, 0.f, 0.f, 0.f};
    }

  int srow = t >> 3;
  int scol = (((t & 7) ^ ((t >> 3) & 7)) * 8);
  int rid[4];
#pragma unroll
  for (int i = 0; i < 4; i++) {
    int r = m0 + srow + 32 * i;
    rid[i] = (e < 8) ? ((r < ne) ? idx[e * NTOK + r] : 0) : r;
  }
  const bf16* gg = BgT + (size_t)e * I_ * H_ + (size_t)(n0 + srow) * H_ + scol;
  const bf16* gu = BuT + (size_t)e * I_ * H_ + (size_t)(n0 + srow) * H_ + scol;
  bf16* la = As + w * 512;
  bf16* lg = Bgs + w * 512;
  bf16* lu = Bus + w * 512;

  for (int k0 = 0; k0 < H_; k0 += 64) {
#pragma unroll
    for (int i = 0; i < 4; i++) {
      gload16(X + (size_t)rid[i] * H_ + scol + k0, la + i * 2048);
      gload16(gg + (size_t)i * 32 * H_ + k0, lg + i * 2048);
      gload16(gu + (size_t)i * 32 * H_ + k0, lu + i * 2048);
    }
    __syncthreads();
#pragma unroll
    for (int ks = 0; ks < 2; ks++) {
      int ko = (((ks * 4 + (l >> 4)) ^ (l & 7)) * 8);
      int ar = wm * 64 + (l & 15);
      int br = wn * 64 + (l & 15);
      bf16x8 af[4], bg[4], bu[4];
#pragma unroll
      for (int mi = 0; mi < 4; mi++)
        af[mi] = *(const bf16x8*)(As + (ar + mi * 16) * 64 + ko);
#pragma unroll
      for (int ni = 0; ni < 4; ni++) {
        bg[ni] = *(const bf16x8*)(Bgs + (br + ni * 16) * 64 + ko);
        bu[ni] = *(const bf16x8*)(Bus + (br + ni * 16) * 64 + ko);
      }
#pragma unroll
      for (int mi = 0; mi < 4; mi++)
#pragma unroll
        for (int ni = 0; ni < 4; ni++) {
          accg[mi][ni] = __builtin_amdgcn_mfma_f32_16x16x32_bf16(af[mi], bg[ni], accg[mi][ni], 0, 0, 0);
          accu[mi][ni] = __builtin_amdgcn_mfma_f32_16x16x32_bf16(af[mi], bu[ni], accu[mi][ni], 0, 0, 0);
        }
    }
    __syncthreads();
  }
#pragma unroll
  for (int mi = 0; mi < 4; mi++) {
#pragma unroll
    for (int r = 0; r < 4; r++) {
      int lr = wm * 64 + mi * 16 + (l >> 4) * 4 + r;
      int pr = m0 + lr;
      if (pr < ne) {
        float c = (e < 8) ? cwp[e * NTOK + pr] : 1.0f;
#pragma unroll
        for (int ni = 0; ni < 4; ni++) {
          float g = accg[mi][ni][r];
          float u = accu[mi][ni][r];
          float val = c * (g / (1.f + __expf(-g))) * u;
          int col = n0 + wn * 64 + ni * 16 + (l & 15);
          Tc[((size_t)e * NTOK + pr) * I_ + col] = (bf16)val;
        }
      }
    }
  }
}

// ---------------- GEMM2 shared: out = Tc[8] @ WdT[8]^T (plain fp32 store) ----------------
__global__ __launch_bounds__(256, 3) void gemm2s_kernel(
    const bf16* __restrict__ Tc, const bf16* __restrict__ WdT,
    float* __restrict__ out) {
  __shared__ bf16 As[128 * 64], Bs[128 * 64];
  int t = threadIdx.x;
  int l = t & 63, w = t >> 6;
  int wm = w >> 1, wn = w & 1;
  int m0 = blockIdx.y * 128;
  int n0 = blockIdx.x * 128;

  f32x4 acc[4][4];
#pragma unroll
  for (int mi = 0; mi < 4; mi++)
#pragma unroll
    for (int ni = 0; ni < 4; ni++) acc[mi][ni] = (f32x4){0.f, 0.f, 0.f, 0.f};

  int srow = t >> 3;
  int scol = (((t & 7) ^ ((t >> 3) & 7)) * 8);
  const bf16* ga = Tc + (size_t)8 * NTOK * I_ + (size_t)(m0 + srow) * I_ + scol;
  const bf16* gb = WdT + (size_t)8 * H_ * I_ + (size_t)(n0 + srow) * I_ + scol;
  bf16* la = As + w * 512;
  bf16* lb = Bs + w * 512;

  for (int k0 = 0; k0 < I_; k0 += 64) {
#pragma unroll
    for (int i = 0; i < 4; i++) {
      gload16(ga + (size_t)i * 32 * I_ + k0, la + i * 2048);
      gload16(gb + (size_t)i * 32 * I_ + k0, lb + i * 2048);
    }
    __syncthreads();
#pragma unroll
    for (int ks = 0; ks < 2; ks++) {
      int ko = (((ks * 4 + (l >> 4)) ^ (l & 7)) * 8);
      int ar = wm * 64 + (l & 15);
      int br = wn * 64 + (l & 15);
      bf16x8 af[4], bfv[4];
#pragma unroll
      for (int mi = 0; mi < 4; mi++)
        af[mi] = *(const bf16x8*)(As + (ar + mi * 16) * 64 + ko);
#pragma unroll
      for (int ni = 0; ni < 4; ni++)
        bfv[ni] = *(const bf16x8*)(Bs + (br + ni * 16) * 64 + ko);
#pragma unroll
      for (int mi = 0; mi < 4; mi++)
#pragma unroll
        for (int ni = 0; ni < 4; ni++)
          acc[mi][ni] = __builtin_amdgcn_mfma_f32_16x16x32_bf16(af[mi], bfv[ni], acc[mi][ni], 0, 0, 0);
    }
    __syncthreads();
  }
#pragma unroll
  for (int mi = 0; mi < 4; mi++) {
#pragma unroll
    for (int r = 0; r < 4; r++) {
      int row = m0 + wm * 64 + mi * 16 + (l >> 4) * 4 + r;
#pragma unroll
      for (int ni = 0; ni < 4; ni++) {
        int col = n0 + wn * 64 + ni * 16 + (l & 15);
        out[(size_t)row * H_ + col] = acc[mi][ni][r];
      }
    }
  }
}

// ---------------- GEMM2 routed (grouped): Yp[off[e]+p] = Tc[e] @ WdT[e]^T ----------------
// Plain coalesced bf16 stores into compacted partial buffer (no atomics).
__global__ __launch_bounds__(256, 3) void gemm2r_kernel(
    const bf16* __restrict__ Tc, const bf16* __restrict__ WdT,
    const int* __restrict__ cnt, bf16* __restrict__ Yp) {
  int slot = blockIdx.y;
  int e = slot >> 6;
  int m0 = (slot & 63) * 128;
  int ne = cnt[e];
  if (m0 >= ne) return;
  int off_e = 0;
  for (int ee = 0; ee < e; ee++) off_e += cnt[ee];   // 8-entry prefix, uniform

  __shared__ bf16 As[128 * 64], Bs[128 * 64];
  int t = threadIdx.x;
  int l = t & 63, w = t >> 6;
  int wm = w >> 1, wn = w & 1;
  int n0 = blockIdx.x * 128;

  f32x4 acc[4][4];
#pragma unroll
  for (int mi = 0; mi < 4; mi++)
#pragma unroll
    for (int ni = 0; ni < 4; ni++) acc[mi][ni] = (f32x4){0.f, 0.f, 0.f, 0.f};

  int srow = t >> 3;
  int scol = (((t & 7) ^ ((t >> 3) & 7)) * 8);
  const bf16* ga = Tc + (size_t)e * NTOK * I_ + (size_t)(m0 + srow) * I_ + scol;
  const bf16* gb = WdT + (size_t)e * H_ * I_ + (size_t)(n0 + srow) * I_ + scol;
  bf16* la = As + w * 512;
  bf16* lb = Bs + w * 512;

  for (int k0 = 0; k0 < I_; k0 += 64) {
#pragma unroll
    for (int i = 0; i < 4; i++) {
      gload16(ga + (size_t)i * 32 * I_ + k0, la + i * 2048);
      gload16(gb + (size_t)i * 32 * I_ + k0, lb + i * 2048);
    }
    __syncthreads();
#pragma unroll
    for (int ks = 0; ks < 2; ks++) {
      int ko = (((ks * 4 + (l >> 4)) ^ (l & 7)) * 8);
      int ar = wm * 64 + (l & 15);
      int br = wn * 64 + (l & 15);
      bf16x8 af[4], bfv[4];
#pragma unroll
      for (int mi = 0; mi < 4; mi++)
        af[mi] = *(const bf16x8*)(As + (ar + mi * 16) * 64 + ko);
#pragma unroll
      for (int ni = 0; ni < 4; ni++)
        bfv[ni] = *(const bf16x8*)(Bs + (br + ni * 16) * 64 + ko);
#pragma unroll
      for (int mi = 0; mi < 4; mi++)
#pragma unroll
        for (int ni = 0; ni < 4; ni++)
          acc[mi][ni] = __builtin_amdgcn_mfma_f32_16x16x32_bf16(af[mi], bfv[ni], acc[mi][ni], 0, 0, 0);
    }
    __syncthreads();
  }
#pragma unroll
  for (int mi = 0; mi < 4; mi++) {
#pragma unroll
    for (int r = 0; r < 4; r++) {
      int lr = wm * 64 + mi * 16 + (l >> 4) * 4 + r;
      int pr = m0 + lr;
      if (pr < ne) {
#pragma unroll
        for (int ni = 0; ni < 4; ni++) {
          int col = n0 + wn * 64 + ni * 16 + (l & 15);
          Yp[(size_t)(off_e + pr) * H_ + col] = (bf16)acc[mi][ni][r];
        }
      }
    }
  }
}

// ---------------- combine: out[n] += sum_j Yp[off[e_j]+p_j] ----------------
__global__ __launch_bounds__(256) void combine_kernel(
    const int* __restrict__ cnt, const int* __restrict__ tokpos,
    const bf16* __restrict__ Yp, float* __restrict__ out) {
  int t = threadIdx.x;
  int tok = blockIdx.x * 2 + (t >> 7);
  int cb = (t & 127) * 8;
  int off[E_];
  int a = 0;
#pragma unroll
  for (int e = 0; e < E_; e++) { off[e] = a; a += cnt[e]; }
  float* op = out + (size_t)tok * H_ + cb;
  f32x4 o0 = *(const f32x4*)(op);
  f32x4 o1 = *(const f32x4*)(op + 4);
  float sum[8] = {o0.x, o0.y, o0.z, o0.w, o1.x, o1.y, o1.z, o1.w};
#pragma unroll
  for (int j = 0; j < 4; j++) {
    int tp = tokpos[tok * 4 + j];
    int e = tp >> 13, p = tp & 8191;
    bf16x8 v = *(const bf16x8*)(Yp + (size_t)(off[e] + p) * H_ + cb);
#pragma unroll
    for (int q = 0; q < 8; q++) sum[q] += (float)v[q];
  }
  *(f32x4*)(op) = (f32x4){sum[0], sum[1], sum[2], sum[3]};
  *(f32x4*)(op + 4) = (f32x4){sum[4], sum[5], sum[6], sum[7]};
}

extern "C" void kernel_launch(void* const* d_in, const int* in_sizes, int n_in,
                              void* d_out, int out_size, void* d_ws, size_t ws_size,
                              hipStream_t stream) {
  const float* x   = (const float*)d_in[0];
  const float* gw  = (const float*)d_in[1];
  const float* cb  = (const float*)d_in[2];
  const float* Wg  = (const float*)d_in[3];
  const float* Wu  = (const float*)d_in[4];
  const float* Wd  = (const float*)d_in[5];
  const float* Wgs = (const float*)d_in[6];
  const float* Wus = (const float*)d_in[7];
  const float* Wds = (const float*)d_in[8];

  char* ws = (char*)d_ws;
  size_t off = 0;
  int*    cnt    = (int*)(ws + off);    off += 64;
  int*    idx    = (int*)(ws + off);    off += (size_t)E_ * NTOK * 4;
  float*  cwp    = (float*)(ws + off);  off += (size_t)E_ * NTOK * 4;
  int4*   topk_e = (int4*)(ws + off);   off += (size_t)NTOK * 16;
  float4* topk_w = (float4*)(ws + off); off += (size_t)NTOK * 16;
  int*    tokpos = (int*)(ws + off);    off += (size_t)NTOK * 4 * 4;
  bf16* BgT = (bf16*)(ws + off);  off += (size_t)NE * I_ * H_ * 2;
  bf16* BuT = (bf16*)(ws + off);  off += (size_t)NE * I_ * H_ * 2;
  bf16* WdT = (bf16*)(ws + off);  off += (size_t)NE * H_ * I_ * 2;
  bf16* Xb  = (bf16*)(ws + off);  off += (size_t)NTOK * H_ * 2;
  bf16* Tc  = (bf16*)(ws + off);  off += (size_t)NE * NTOK * I_ * 2;
  bf16* Yp  = (bf16*)(ws + off);  off += (size_t)4 * NTOK * H_ * 2;   // 32768 partial rows

  hipMemsetAsync(cnt, 0, 64, stream);
  hipLaunchKernelGGL(convert_kernel, dim3(NTOK * H_ / 1024), dim3(256), 0, stream,
                     x, Xb);
  hipLaunchKernelGGL(transpose_kernel, dim3(27 * 512), dim3(256), 0, stream,
                     Wg, Wu, Wd, Wgs, Wus, Wds, BgT, BuT, WdT);
  hipLaunchKernelGGL(router_kernel, dim3(NTOK / 4), dim3(256), 0, stream,
                     x, gw, cb, topk_e, topk_w);
  hipLaunchKernelGGL(compact_kernel, dim3(NTOK / 256), dim3(256), 0, stream,
                     topk_e, topk_w, cnt, idx, cwp, tokpos);
  hipLaunchKernelGGL(gemm1_kernel, dim3(4, NE * 64), dim3(256), 0, stream,
                     Xb, BgT, BuT, idx, cwp, cnt, Tc);
  hipLaunchKernelGGL(gemm2s_kernel, dim3(8, 64), dim3(256), 0, stream,
                     Tc, WdT, (float*)d_out);
  hipLaunchKernelGGL(gemm2r_kernel, dim3(8, E_ * 64), dim3(256), 0, stream,
                     Tc, WdT, cnt, Yp);
  hipLaunchKernelGGL(combine_kernel, dim3(NTOK / 2), dim3(256), 0, stream,
                     cnt, tokpos, Yp, (float*)d_out);
}

// Round 7
// 379.362 us; speedup vs baseline: 2.0566x; 1.0226x over previous
//
#include <hip/hip_runtime.h>

#define E_ 8
#define H_ 1024
#define I_ 512
#define NE 9            // 8 routed + 1 shared
#define NTOK 8192
#define NROWS 40960     // 4*NTOK routed + NTOK shared compacted rows

typedef __bf16 bf16;
typedef __bf16 bf16x8 __attribute__((ext_vector_type(8)));
typedef __bf16 bf16x4 __attribute__((ext_vector_type(4)));
typedef float f32x4 __attribute__((ext_vector_type(4)));

__device__ __forceinline__ void gload16(const bf16* g, bf16* l) {
  __builtin_amdgcn_global_load_lds(
      (const __attribute__((address_space(1))) void*)g,
      (__attribute__((address_space(3))) void*)l,
      16, 0, 0);
}

// ---------------- prep: convert (x->bf16) + weight transpose + router ----------------
// blocks [0,2048): convert; [2048,5504): transpose (27 jobs x 128 64x64-tiles);
// [5504,7552): router (4 tokens/block).
#define PREP_CONV 2048
#define PREP_TRANS 3456
__global__ __launch_bounds__(256) void prep_kernel(
    const float* __restrict__ x, const float* __restrict__ gw,
    const float* __restrict__ bias,
    const float* __restrict__ Wg, const float* __restrict__ Wu,
    const float* __restrict__ Wd, const float* __restrict__ Wgs,
    const float* __restrict__ Wus, const float* __restrict__ Wds,
    bf16* __restrict__ xb, bf16* __restrict__ BgT, bf16* __restrict__ BuT,
    bf16* __restrict__ WdT, int4* __restrict__ topk_e, float4* __restrict__ topk_w) {
  __shared__ bf16 tile[64][66];
  int bid = blockIdx.x;
  int t = threadIdx.x;

  if (bid < PREP_CONV) {
    // ---- convert: 4 f32x4 per thread ----
    size_t base = (size_t)bid * 1024 + t;
#pragma unroll
    for (int j = 0; j < 4; j++) {
      f32x4 v = ((const f32x4*)x)[base + 256 * j];
      bf16x4 o = {(bf16)v.x, (bf16)v.y, (bf16)v.z, (bf16)v.w};
      ((bf16x4*)xb)[base + 256 * j] = o;
    }
    return;
  }
  if (bid < PREP_CONV + PREP_TRANS) {
    // ---- transpose + fp32->bf16: 64x64 tile ----
    int b = bid - PREP_CONV;
    int job = b >> 7;
    int tl = b & 127;
    const float* src;
    bf16* dst;
    int C, dst_ld, tr, tc;
    if (job < 18) {
      int e = job % 9;
      if (job < 9) src = (e < 8) ? Wg + (size_t)e * H_ * I_ : Wgs;
      else         src = (e < 8) ? Wu + (size_t)e * H_ * I_ : Wus;
      dst = ((job < 9) ? BgT : BuT) + (size_t)e * I_ * H_;
      C = I_; dst_ld = H_;                 // [1024,512] -> [512,1024]
      tr = tl >> 3; tc = tl & 7;           // 16 x 8 tiles
    } else {
      int e = job - 18;
      src = (e < 8) ? Wd + (size_t)e * I_ * H_ : Wds;   // [512,1024]
      dst = WdT + (size_t)e * H_ * I_;                  // [1024,512]
      C = H_; dst_ld = I_;
      tr = tl >> 4; tc = tl & 15;          // 8 x 16 tiles
    }
    int lx = t & 63, ly = t >> 6;
#pragma unroll
    for (int j = 0; j < 16; j++) {
      int rl = j * 4 + ly;
      tile[lx][rl] = (bf16)src[(size_t)(tr * 64 + rl) * C + tc * 64 + lx];
    }
    __syncthreads();
#pragma unroll
    for (int j = 0; j < 16; j++) {
      int cl = j * 4 + ly;
      dst[(size_t)(tc * 64 + cl) * dst_ld + tr * 64 + lx] = tile[cl][lx];
    }
    return;
  }
  // ---- router: 1 wave per token, fp32 math, interleaved butterfly ----
  int rb = bid - PREP_CONV - PREP_TRANS;
  int l = t & 63, w = t >> 6;
  int n = rb * 4 + w;
  const f32x4* xr = (const f32x4*)(x + (size_t)n * H_ + l * 16);
  float xv[16];
#pragma unroll
  for (int q = 0; q < 4; q++) {
    f32x4 v = xr[q];
    xv[q * 4 + 0] = v.x; xv[q * 4 + 1] = v.y; xv[q * 4 + 2] = v.z; xv[q * 4 + 3] = v.w;
  }
  float acc[E_];
#pragma unroll
  for (int e = 0; e < E_; e++) {
    const f32x4* gr = (const f32x4*)(gw + e * H_ + l * 16);
    float a = 0.f;
#pragma unroll
    for (int q = 0; q < 4; q++) {
      f32x4 g = gr[q];
      a += xv[q * 4 + 0] * g.x + xv[q * 4 + 1] * g.y + xv[q * 4 + 2] * g.z + xv[q * 4 + 3] * g.w;
    }
    acc[e] = a;
  }
#pragma unroll
  for (int off = 32; off > 0; off >>= 1) {
    float tmp[E_];
#pragma unroll
    for (int e = 0; e < E_; e++) tmp[e] = __shfl_xor(acc[e], off, 64);  // 8 independent shfls/level
#pragma unroll
    for (int e = 0; e < E_; e++) acc[e] += tmp[e];
  }
  if (l == 0) {
    float s[E_], sc[E_];
#pragma unroll
    for (int e = 0; e < E_; e++) {
      s[e] = 1.f / (1.f + __expf(-acc[e]));
      sc[e] = s[e] + bias[e];
    }
    float gs[4];
#pragma unroll
    for (int g = 0; g < 4; g++) gs[g] = sc[2 * g] + sc[2 * g + 1];
    int g0 = 0;
    for (int g = 1; g < 4; g++) if (gs[g] > gs[g0]) g0 = g;
    int g1 = -1;
    for (int g = 0; g < 4; g++) {
      if (g == g0) continue;
      if (g1 < 0 || gs[g] > gs[g1]) g1 = g;
    }
    int es[4] = {2 * g0, 2 * g0 + 1, 2 * g1, 2 * g1 + 1};
    float wsum = 1e-20f;
    for (int j = 0; j < 4; j++) wsum += s[es[j]];
    float inv = 2.5f / wsum;
    topk_e[n] = (int4){es[0], es[1], es[2], es[3]};
    topk_w[n] = (float4){s[es[0]] * inv, s[es[1]] * inv, s[es[2]] * inv, s[es[3]] * inv};
  }
}

// ---------------- compaction: per-expert token lists, block-aggregated atomics ----------------
__global__ __launch_bounds__(256) void compact_kernel(
    const int4* __restrict__ topk_e, const float4* __restrict__ topk_w,
    int* __restrict__ cnt, int* __restrict__ idx, float* __restrict__ cwp,
    int* __restrict__ tokpos) {
  __shared__ int hist[E_];
  __shared__ int base[E_];
  int t = threadIdx.x;
  if (t < E_) hist[t] = 0;
  __syncthreads();
  int n = blockIdx.x * 256 + t;
  int4 e4 = topk_e[n];
  float4 w4 = topk_w[n];
  int le[4] = {e4.x, e4.y, e4.z, e4.w};
  float lw[4] = {w4.x, w4.y, w4.z, w4.w};
  int lpos[4];
#pragma unroll
  for (int j = 0; j < 4; j++) lpos[j] = atomicAdd(&hist[le[j]], 1);
  __syncthreads();
  if (t < E_) base[t] = atomicAdd(&cnt[t], hist[t]);   // 8 global atomics / block
  __syncthreads();
#pragma unroll
  for (int j = 0; j < 4; j++) {
    int p = base[le[j]] + lpos[j];
    idx[le[j] * NTOK + p] = n;
    cwp[le[j] * NTOK + p] = lw[j];
    tokpos[n * 4 + j] = (le[j] << 13) | p;     // packed (expert, pos)
  }
}

// slot -> (expert, m0, off_e): scan cnt. Returns false if slot beyond work.
__device__ __forceinline__ bool slot_decode(const int* cnt, int slot,
                                            int& e, int& m0, int& ne, int& off_e) {
  int off = 0, s = slot;
  for (int ee = 0; ee < NE; ee++) {
    int c = (ee < E_) ? cnt[ee] : NTOK;
    int tl = (c + 127) >> 7;
    if (s < tl) { e = ee; m0 = s * 128; ne = c; off_e = off; return true; }
    s -= tl;
    off += c;
  }
  return false;
}

// LDS tiles [128][64] bf16, XOR-swizzled in 16B chunks (see R2 notes):
// store chunk (l&7) holds global chunk (l&7)^((l>>3)&7); fragment read of
// global chunk q at row r uses chunk q^(r&7); row offsets are multiples of 8
// so swizzle = q^(l&7) -> 2-way conflicts only (free).

// ---------------- GEMM1 (grouped): Tc[off_e+p] = cw*silu(X Wg_e)*(X Wu_e) ----------------
// grid.x = 4 n-tiles, grid.y = 328 flattened tile slots
__global__ __launch_bounds__(256, 2) void gemm1_kernel(
    const bf16* __restrict__ X, const bf16* __restrict__ BgT,
    const bf16* __restrict__ BuT, const int* __restrict__ idx,
    const float* __restrict__ cwp, const int* __restrict__ cnt,
    bf16* __restrict__ Tc) {
  int e, m0, ne, off_e;
  if (!slot_decode(cnt, blockIdx.y, e, m0, ne, off_e)) return;

  __shared__ bf16 As[128 * 64], Bgs[128 * 64], Bus[128 * 64];
  int t = threadIdx.x;
  int l = t & 63, w = t >> 6;
  int wm = w >> 1, wn = w & 1;
  int n0 = blockIdx.x * 128;

  f32x4 accg[4][4], accu[4][4];
#pragma unroll
  for (int mi = 0; mi < 4; mi++)
#pragma unroll
    for (int ni = 0; ni < 4; ni++) {
      accg[mi][ni] = (f32x4){0.f, 0.f, 0.f, 0.f};
      accu[mi][ni] = (f32x4){0.f, 0.f, 0.f, 0.f};
    }

  int srow = t >> 3;
  int scol = (((t & 7) ^ ((t >> 3) & 7)) * 8);
  int rid[4];
#pragma unroll
  for (int i = 0; i < 4; i++) {
    int r = m0 + srow + 32 * i;
    rid[i] = (e < 8) ? ((r < ne) ? idx[e * NTOK + r] : 0) : r;
  }
  const bf16* gg = BgT + (size_t)e * I_ * H_ + (size_t)(n0 + srow) * H_ + scol;
  const bf16* gu = BuT + (size_t)e * I_ * H_ + (size_t)(n0 + srow) * H_ + scol;
  bf16* la = As + w * 512;
  bf16* lg = Bgs + w * 512;
  bf16* lu = Bus + w * 512;

  for (int k0 = 0; k0 < H_; k0 += 64) {
#pragma unroll
    for (int i = 0; i < 4; i++) {
      gload16(X + (size_t)rid[i] * H_ + scol + k0, la + i * 2048);
      gload16(gg + (size_t)i * 32 * H_ + k0, lg + i * 2048);
      gload16(gu + (size_t)i * 32 * H_ + k0, lu + i * 2048);
    }
    __syncthreads();
#pragma unroll
    for (int ks = 0; ks < 2; ks++) {
      int ko = (((ks * 4 + (l >> 4)) ^ (l & 7)) * 8);
      int ar = wm * 64 + (l & 15);
      int br = wn * 64 + (l & 15);
      bf16x8 af[4], bg[4], bu[4];
#pragma unroll
      for (int mi = 0; mi < 4; mi++)
        af[mi] = *(const bf16x8*)(As + (ar + mi * 16) * 64 + ko);
#pragma unroll
      for (int ni = 0; ni < 4; ni++) {
        bg[ni] = *(const bf16x8*)(Bgs + (br + ni * 16) * 64 + ko);
        bu[ni] = *(const bf16x8*)(Bus + (br + ni * 16) * 64 + ko);
      }
#pragma unroll
      for (int mi = 0; mi < 4; mi++)
#pragma unroll
        for (int ni = 0; ni < 4; ni++) {
          accg[mi][ni] = __builtin_amdgcn_mfma_f32_16x16x32_bf16(af[mi], bg[ni], accg[mi][ni], 0, 0, 0);
          accu[mi][ni] = __builtin_amdgcn_mfma_f32_16x16x32_bf16(af[mi], bu[ni], accu[mi][ni], 0, 0, 0);
        }
    }
    __syncthreads();
  }
#pragma unroll
  for (int mi = 0; mi < 4; mi++) {
#pragma unroll
    for (int r = 0; r < 4; r++) {
      int lr = wm * 64 + mi * 16 + (l >> 4) * 4 + r;
      int pr = m0 + lr;
      if (pr < ne) {
        float c = (e < 8) ? cwp[e * NTOK + pr] : 1.0f;
#pragma unroll
        for (int ni = 0; ni < 4; ni++) {
          float g = accg[mi][ni][r];
          float u = accu[mi][ni][r];
          float val = c * (g / (1.f + __expf(-g))) * u;
          int col = n0 + wn * 64 + ni * 16 + (l & 15);
          Tc[(size_t)(off_e + pr) * I_ + col] = (bf16)val;
        }
      }
    }
  }
}

// ---------------- GEMM2 (grouped, all 9 experts): Yp[off_e+p] = Tc @ WdT_e^T ----------------
// grid.x = 8 n-tiles over H, grid.y = 328 flattened slots; bf16 stores, no atomics.
__global__ __launch_bounds__(256, 3) void gemm2_kernel(
    const bf16* __restrict__ Tc, const bf16* __restrict__ WdT,
    const int* __restrict__ cnt, bf16* __restrict__ Yp) {
  int e, m0, ne, off_e;
  if (!slot_decode(cnt, blockIdx.y, e, m0, ne, off_e)) return;

  __shared__ bf16 As[128 * 64], Bs[128 * 64];
  int t = threadIdx.x;
  int l = t & 63, w = t >> 6;
  int wm = w >> 1, wn = w & 1;
  int n0 = blockIdx.x * 128;

  f32x4 acc[4][4];
#pragma unroll
  for (int mi = 0; mi < 4; mi++)
#pragma unroll
    for (int ni = 0; ni < 4; ni++) acc[mi][ni] = (f32x4){0.f, 0.f, 0.f, 0.f};

  int srow = t >> 3;
  int scol = (((t & 7) ^ ((t >> 3) & 7)) * 8);
  const bf16* ga = Tc + (size_t)(off_e + m0 + srow) * I_ + scol;
  const bf16* gb = WdT + (size_t)e * H_ * I_ + (size_t)(n0 + srow) * I_ + scol;
  bf16* la = As + w * 512;
  bf16* lb = Bs + w * 512;

  for (int k0 = 0; k0 < I_; k0 += 64) {
#pragma unroll
    for (int i = 0; i < 4; i++) {
      gload16(ga + (size_t)i * 32 * I_ + k0, la + i * 2048);
      gload16(gb + (size_t)i * 32 * I_ + k0, lb + i * 2048);
    }
    __syncthreads();
#pragma unroll
    for (int ks = 0; ks < 2; ks++) {
      int ko = (((ks * 4 + (l >> 4)) ^ (l & 7)) * 8);
      int ar = wm * 64 + (l & 15);
      int br = wn * 64 + (l & 15);
      bf16x8 af[4], bfv[4];
#pragma unroll
      for (int mi = 0; mi < 4; mi++)
        af[mi] = *(const bf16x8*)(As + (ar + mi * 16) * 64 + ko);
#pragma unroll
      for (int ni = 0; ni < 4; ni++)
        bfv[ni] = *(const bf16x8*)(Bs + (br + ni * 16) * 64 + ko);
#pragma unroll
      for (int mi = 0; mi < 4; mi++)
#pragma unroll
        for (int ni = 0; ni < 4; ni++)
          acc[mi][ni] = __builtin_amdgcn_mfma_f32_16x16x32_bf16(af[mi], bfv[ni], acc[mi][ni], 0, 0, 0);
    }
    __syncthreads();
  }
#pragma unroll
  for (int mi = 0; mi < 4; mi++) {
#pragma unroll
    for (int r = 0; r < 4; r++) {
      int lr = wm * 64 + mi * 16 + (l >> 4) * 4 + r;
      int pr = m0 + lr;
      if (pr < ne) {
#pragma unroll
        for (int ni = 0; ni < 4; ni++) {
          int col = n0 + wn * 64 + ni * 16 + (l & 15);
          Yp[(size_t)(off_e + pr) * H_ + col] = (bf16)acc[mi][ni][r];
        }
      }
    }
  }
}

// ---------------- combine: out[n] = sum of 4 routed partial rows + shared row ----------------
__global__ __launch_bounds__(256) void combine_kernel(
    const int* __restrict__ cnt, const int* __restrict__ tokpos,
    const bf16* __restrict__ Yp, float* __restrict__ out) {
  int t = threadIdx.x;
  int tok = blockIdx.x * 2 + (t >> 7);
  int cb = (t & 127) * 8;
  int off[E_];
  int a = 0;
#pragma unroll
  for (int e = 0; e < E_; e++) { off[e] = a; a += cnt[e]; }
  float sum[8];
  {
    bf16x8 v = *(const bf16x8*)(Yp + (size_t)(32768 + tok) * H_ + cb);  // shared
#pragma unroll
    for (int q = 0; q < 8; q++) sum[q] = (float)v[q];
  }
#pragma unroll
  for (int j = 0; j < 4; j++) {
    int tp = tokpos[tok * 4 + j];
    int e = tp >> 13, p = tp & 8191;
    bf16x8 v = *(const bf16x8*)(Yp + (size_t)(off[e] + p) * H_ + cb);
#pragma unroll
    for (int q = 0; q < 8; q++) sum[q] += (float)v[q];
  }
  float* op = out + (size_t)tok * H_ + cb;
  *(f32x4*)(op) = (f32x4){sum[0], sum[1], sum[2], sum[3]};
  *(f32x4*)(op + 4) = (f32x4){sum[4], sum[5], sum[6], sum[7]};
}

extern "C" void kernel_launch(void* const* d_in, const int* in_sizes, int n_in,
                              void* d_out, int out_size, void* d_ws, size_t ws_size,
                              hipStream_t stream) {
  const float* x   = (const float*)d_in[0];
  const float* gw  = (const float*)d_in[1];
  const float* cb  = (const float*)d_in[2];
  const float* Wg  = (const float*)d_in[3];
  const float* Wu  = (const float*)d_in[4];
  const float* Wd  = (const float*)d_in[5];
  const float* Wgs = (const float*)d_in[6];
  const float* Wus = (const float*)d_in[7];
  const float* Wds = (const float*)d_in[8];

  char* ws = (char*)d_ws;
  size_t off = 0;
  int*    cnt    = (int*)(ws + off);    off += 64;
  int*    idx    = (int*)(ws + off);    off += (size_t)E_ * NTOK * 4;
  float*  cwp    = (float*)(ws + off);  off += (size_t)E_ * NTOK * 4;
  int4*   topk_e = (int4*)(ws + off);   off += (size_t)NTOK * 16;
  float4* topk_w = (float4*)(ws + off); off += (size_t)NTOK * 16;
  int*    tokpos = (int*)(ws + off);    off += (size_t)NTOK * 4 * 4;
  bf16* BgT = (bf16*)(ws + off);  off += (size_t)NE * I_ * H_ * 2;
  bf16* BuT = (bf16*)(ws + off);  off += (size_t)NE * I_ * H_ * 2;
  bf16* WdT = (bf16*)(ws + off);  off += (size_t)NE * H_ * I_ * 2;
  bf16* Xb  = (bf16*)(ws + off);  off += (size_t)NTOK * H_ * 2;
  bf16* Tc  = (bf16*)(ws + off);  off += (size_t)NROWS * I_ * 2;
  bf16* Yp  = (bf16*)(ws + off);  off += (size_t)NROWS * H_ * 2;

  hipMemsetAsync(cnt, 0, 64, stream);
  hipLaunchKernelGGL(prep_kernel, dim3(PREP_CONV + PREP_TRANS + NTOK / 4), dim3(256), 0, stream,
                     x, gw, cb, Wg, Wu, Wd, Wgs, Wus, Wds,
                     Xb, BgT, BuT, WdT, topk_e, topk_w);
  hipLaunchKernelGGL(compact_kernel, dim3(NTOK / 256), dim3(256), 0, stream,
                     topk_e, topk_w, cnt, idx, cwp, tokpos);
  hipLaunchKernelGGL(gemm1_kernel, dim3(4, 328), dim3(256), 0, stream,
                     Xb, BgT, BuT, idx, cwp, cnt, Tc);
  hipLaunchKernelGGL(gemm2_kernel, dim3(8, 328), dim3(256), 0, stream,
                     Tc, WdT, cnt, Yp);
  hipLaunchKernelGGL(combine_kernel, dim3(NTOK / 2), dim3(256), 0, stream,
                     cnt, tokpos, Yp, (float*)d_out);
}